// Round 14
// baseline (318.711 us; speedup 1.0000x reference)
//
#include <hip/hip_runtime.h>
#include <math.h>
#include <stdint.h>

typedef __attribute__((ext_vector_type(8))) short short8;
typedef __attribute__((ext_vector_type(4))) float f32x4;

__device__ __forceinline__ uint32_t cvt_pk_bf16(float lo, float hi) {
  uint32_t r;
  asm("v_cvt_pk_bf16_f32 %0, %1, %2" : "=v"(r) : "v"(lo), "v"(hi));
  return r;
}

// inverse-distance weight; invalid j has cx=cy=1e30 -> d2 overflows to inf
// -> rcp(inf)=0, so invalid columns contribute exactly 0.
__device__ __forceinline__ float wfun(float hx, float hy, float cx, float cy) {
  float dx = hx - cx, dy = hy - cy;
  float d = __builtin_amdgcn_sqrtf(fmaf(dx, dx, dy * dy));
  return __builtin_amdgcn_rcpf(d + 1e-4f);
}

// ---------------------------------------------------------------------------
// Kernel 1: hp = tanh(batch@W_h + b_h); hx,hy,validf,cxy per row. (verified)
__global__ __launch_bounds__(256) void k_head(
    const float* __restrict__ batch, const float* __restrict__ xywh,
    const float* __restrict__ W_h, const float* __restrict__ b_h,
    float* __restrict__ hp_out, float* __restrict__ hx, float* __restrict__ hy,
    float* __restrict__ validf, float2* __restrict__ cxy, int S, int F) {
  int wid = threadIdx.x >> 6;
  int lane = threadIdx.x & 63;
  int row = blockIdx.x * 4 + wid;
  if (row >= S) return;
  const float4* brow = (const float4*)(batch + (size_t)row * F);
  const float4* wh4 = (const float4*)W_h;  // W_h is [F,2] row-major
  int nf4 = F >> 2;
  float acc0 = 0.f, acc1 = 0.f;
  for (int k4 = lane; k4 < nf4; k4 += 64) {
    float4 b = brow[k4];
    float4 wa = wh4[2 * k4];
    float4 wb = wh4[2 * k4 + 1];
    acc0 += b.x * wa.x + b.y * wa.z + b.z * wb.x + b.w * wb.z;
    acc1 += b.x * wa.y + b.y * wa.w + b.z * wb.y + b.w * wb.w;
  }
  #pragma unroll
  for (int off = 32; off; off >>= 1) {
    acc0 += __shfl_xor(acc0, off, 64);
    acc1 += __shfl_xor(acc1, off, 64);
  }
  if (lane == 0) {
    float hp0 = tanhf(acc0 + b_h[0]);
    float hp1 = tanhf(acc1 + b_h[1]);
    float4 xy = ((const float4*)xywh)[row];
    hp_out[2 * row] = hp0;
    hp_out[2 * row + 1] = hp1;
    hx[row] = hp0 * xy.z * 4.0f + xy.x;  // SIGMA_X = 4
    hy[row] = hp1 * xy.w * 1.0f + xy.y;  // SIGMA_Y = 1
    bool v = (xy.x + xy.y + xy.z + xy.w >= 1e-8f);
    validf[row] = v ? 1.0f : 0.0f;
    cxy[row] = v ? make_float2(xy.x, xy.y) : make_float2(1e30f, 1e30f);
  }
}

// ---------------------------------------------------------------------------
// Kernel 1b: WgT[a][k] = bf16(Wg[k][a])  (verified)
__global__ __launch_bounds__(256) void k_prep_w(
    const float* __restrict__ Wg, uint16_t* __restrict__ WgT, int F, int A) {
  int idx = blockIdx.x * 256 + threadIdx.x;
  int a = idx % A;
  int k0 = (idx / A) * 8;
  if (k0 >= F) return;
  float f[8];
  #pragma unroll
  for (int e = 0; e < 8; ++e) f[e] = Wg[(size_t)(k0 + e) * A + a];
  uint4 v;
  v.x = cvt_pk_bf16(f[0], f[1]);
  v.y = cvt_pk_bf16(f[2], f[3]);
  v.z = cvt_pk_bf16(f[4], f[5]);
  v.w = cvt_pk_bf16(f[6], f[7]);
  *(uint4*)(WgT + (size_t)a * F + k0) = v;
}

// ---------------------------------------------------------------------------
// Kernel 2: targets via bf16 MFMA; tiled output tgt2[jb][a][jj]. (verified)
__global__ __launch_bounds__(256) void k_targets_mfma(
    const float* __restrict__ batch, const uint16_t* __restrict__ WgT,
    const float* __restrict__ bg, uint16_t* __restrict__ tgt2,
    int S, int F, int A) {
  int t = threadIdx.x;
  int lane = t & 63, wid = t >> 6;
  int wm = wid >> 1, wn = wid & 1;
  int i0 = blockIdx.x * 32;
  int row = i0 + wm * 16 + (lane & 15);
  int kch = lane >> 4;
  const float* ab = batch + (size_t)row * F + kch * 8;
  int ncol0 = wn * 128 + (lane & 15);
  const uint16_t* bb = WgT + (size_t)ncol0 * F + kch * 8;

  f32x4 acc[8] = {};
  float4 a0 = *(const float4*)(ab);
  float4 a1 = *(const float4*)(ab + 4);
  short8 bf[8];
  #pragma unroll
  for (int nf = 0; nf < 8; ++nf)
    bf[nf] = *(const short8*)(bb + (size_t)nf * 16 * F);

  for (int k0 = 0; k0 < F; k0 += 32) {
    int kn = (k0 + 32 < F) ? k0 + 32 : 0;  // wrap prefetch (harmless)
    float4 na0 = *(const float4*)(ab + kn);
    float4 na1 = *(const float4*)(ab + kn + 4);
    short8 nbf[8];
    #pragma unroll
    for (int nf = 0; nf < 8; ++nf)
      nbf[nf] = *(const short8*)(bb + kn + (size_t)nf * 16 * F);
    union { short8 s; uint32_t u[4]; } af;
    af.u[0] = cvt_pk_bf16(a0.x, a0.y);
    af.u[1] = cvt_pk_bf16(a0.z, a0.w);
    af.u[2] = cvt_pk_bf16(a1.x, a1.y);
    af.u[3] = cvt_pk_bf16(a1.z, a1.w);
    #pragma unroll
    for (int nf = 0; nf < 8; ++nf)
      acc[nf] = __builtin_amdgcn_mfma_f32_16x16x32_bf16(af.s, bf[nf], acc[nf], 0, 0, 0);
    a0 = na0; a1 = na1;
    #pragma unroll
    for (int nf = 0; nf < 8; ++nf) bf[nf] = nbf[nf];
  }

  int jb = blockIdx.x;
  int rloc = wm * 16 + (lane >> 4) * 4;   // row within tile, mult of 4
  #pragma unroll
  for (int nf = 0; nf < 8; ++nf) {
    int col = ncol0 + nf * 16;
    float b = bg[col];
    float o0 = fmaxf(acc[nf][0] + b, 0.f);
    float o1 = fmaxf(acc[nf][1] + b, 0.f);
    float o2 = fmaxf(acc[nf][2] + b, 0.f);
    float o3 = fmaxf(acc[nf][3] + b, 0.f);
    uint2 pk;
    pk.x = cvt_pk_bf16(o0, o1);
    pk.y = cvt_pk_bf16(o2, o3);
    *(uint2*)(tgt2 + ((size_t)jb * A + col) * 32 + rloc) = pk;
  }
}

// ---------------------------------------------------------------------------
// Kernel 3: out = rownorm(W) @ targets. Literal round-13 kernel (113 us
// verified) with ONE change: Bt col stride 40 -> 36 halfwords (72 B -> the
// 16 consecutive-col ds_read_b128 lanes hit 16 distinct banks; writes <=2-way
// which is free). Everything else byte-identical, staging unconditional.
__global__ __launch_bounds__(1024, 4) void k_gather_v14(
    const uint16_t* __restrict__ tgt2, const float2* __restrict__ cxy,
    const float* __restrict__ hx, const float* __restrict__ hy,
    const float* __restrict__ validf, float* __restrict__ out, int S, int A) {
  __shared__ uint16_t Bt[2][2][2][128][36]; // [dbuf][parity][kg][col][36hw] 73.7KB
  __shared__ float2  Ct[2][2][2][32];       // [dbuf][parity][kg][jj]       2KB
  __shared__ float comb[64][132];           // kg=1 partial acc             33.8KB
  __shared__ float rs2[2][64];
  __shared__ float scale_s[64];

  int t = threadIdx.x;
  int lane = t & 63, wid = t >> 6;
  int kg = wid >> 3;                // 0..1
  int sub = wid & 7;
  int wm = sub >> 1, wn = sub & 1;  // 4M x 2N within K-group
  int colhalf = blockIdx.x;         // 0..1
  int i0 = blockIdx.y * 64;
  int mrow = i0 + wm * 16 + (lane & 15);
  int kch = lane >> 4;
  float hx_i = hx[mrow], hy_i = hy[mrow];
  int n0 = wn * 64 + (lane & 15);              // col within block (0..127)
  int NT = (S >> 1) / 32;                      // 128 tiles per K-group
  int nsteps = NT >> 1;                        // 64 double-steps
  const size_t TSTRIDE = (size_t)A * 32;       // elements per j-tile
  const int COLS = 36;                         // Bt col stride in halfwords

  // staging roles: every thread stages 16 B of each parity tile; t<64 stage c.
  int skg = t >> 9;                 // == kg
  int su = t & 511;
  int scol = su >> 2;               // 0..127
  int skw = su & 3;                 // 0..3 (16-B quarter of the 64-B column)
  const uint16_t* gB0 = tgt2 + (size_t)(skg * NT) * TSTRIDE
                        + (size_t)(colhalf * 128 + scol) * 32 + skw * 8;
  int kgc = (t >> 4) & 1;           // c-staging: kg of this c-thread
  int pc  = t >> 5;                 // c-staging: parity (t<64 only)
  int jic = (t & 15) * 2;
  const float2* gC0 = cxy + (size_t)kgc * (S >> 1) + pc * 32 + jic;

  f32x4 acc[4] = {};
  float rs = 0.f;

  // prologue: stage double-step 0 (tiles 0 and 1)
  {
    uint4 ga = *(const uint4*)(gB0);
    uint4 gb = *(const uint4*)(gB0 + TSTRIDE);
    *(uint4*)&Bt[0][0][skg][scol][skw * 8] = ga;
    *(uint4*)&Bt[0][1][skg][scol][skw * 8] = gb;
    if (t < 64) {
      float4 gc = *(const float4*)(gC0);
      *(float4*)&Ct[0][pc][kgc][jic] = gc;
    }
  }
  __syncthreads();

  for (int ts = 0; ts < nsteps; ++ts) {
    int cur = ts & 1, nxt = cur ^ 1;
    int tn = (ts + 1 < nsteps) ? ts + 1 : 0;   // wrap stage (harmless)

    // issue next-double-step global loads (latency hidden by compute)
    const uint16_t* bp = gB0 + (size_t)(2 * tn) * TSTRIDE;
    uint4 ga = *(const uint4*)(bp);
    uint4 gb = *(const uint4*)(bp + TSTRIDE);
    float4 gc;
    if (t < 64) gc = *(const float4*)(gC0 + tn * 64);

    // c from LDS (broadcast within 16-lane groups), both parities
    const float2* cp0 = &Ct[cur][0][kg][kch * 8];
    const float2* cp1 = &Ct[cur][1][kg][kch * 8];
    float4 c0 = *(const float4*)(cp0);
    float4 c1 = *(const float4*)(cp0 + 2);
    float4 c2 = *(const float4*)(cp0 + 4);
    float4 c3 = *(const float4*)(cp0 + 6);
    float4 c4 = *(const float4*)(cp1);
    float4 c5 = *(const float4*)(cp1 + 2);
    float4 c6 = *(const float4*)(cp1 + 4);
    float4 c7 = *(const float4*)(cp1 + 6);

    // B frags from LDS, both parities
    const uint16_t* br0 = &Bt[cur][0][kg][n0][kch * 8];
    const uint16_t* br1 = &Bt[cur][1][kg][n0][kch * 8];
    short8 b0 = *(const short8*)(br0);
    short8 b1 = *(const short8*)(br0 + 16 * COLS);
    short8 b2 = *(const short8*)(br0 + 32 * COLS);
    short8 b3 = *(const short8*)(br0 + 48 * COLS);
    short8 b4 = *(const short8*)(br1);
    short8 b5 = *(const short8*)(br1 + 16 * COLS);
    short8 b6 = *(const short8*)(br1 + 32 * COLS);
    short8 b7 = *(const short8*)(br1 + 48 * COLS);

    // 16 w's: 8 per parity tile (A layout row=lane&15, k=(lane>>4)*8+e)
    float w0 = wfun(hx_i, hy_i, c0.x, c0.y);
    float w1 = wfun(hx_i, hy_i, c0.z, c0.w);
    float w2 = wfun(hx_i, hy_i, c1.x, c1.y);
    float w3 = wfun(hx_i, hy_i, c1.z, c1.w);
    float w4 = wfun(hx_i, hy_i, c2.x, c2.y);
    float w5 = wfun(hx_i, hy_i, c2.z, c2.w);
    float w6 = wfun(hx_i, hy_i, c3.x, c3.y);
    float w7 = wfun(hx_i, hy_i, c3.z, c3.w);
    float w8 = wfun(hx_i, hy_i, c4.x, c4.y);
    float w9 = wfun(hx_i, hy_i, c4.z, c4.w);
    float wa = wfun(hx_i, hy_i, c5.x, c5.y);
    float wb = wfun(hx_i, hy_i, c5.z, c5.w);
    float wc = wfun(hx_i, hy_i, c6.x, c6.y);
    float wd = wfun(hx_i, hy_i, c6.z, c6.w);
    float we = wfun(hx_i, hy_i, c7.x, c7.y);
    float wf = wfun(hx_i, hy_i, c7.z, c7.w);
    rs += (((w0 + w1) + (w2 + w3)) + ((w4 + w5) + (w6 + w7)))
        + (((w8 + w9) + (wa + wb)) + ((wc + wd) + (we + wf)));
    union { short8 s; uint32_t u[4]; } af0, af1;
    af0.u[0] = cvt_pk_bf16(w0, w1);
    af0.u[1] = cvt_pk_bf16(w2, w3);
    af0.u[2] = cvt_pk_bf16(w4, w5);
    af0.u[3] = cvt_pk_bf16(w6, w7);
    af1.u[0] = cvt_pk_bf16(w8, w9);
    af1.u[1] = cvt_pk_bf16(wa, wb);
    af1.u[2] = cvt_pk_bf16(wc, wd);
    af1.u[3] = cvt_pk_bf16(we, wf);

    acc[0] = __builtin_amdgcn_mfma_f32_16x16x32_bf16(af0.s, b0, acc[0], 0, 0, 0);
    acc[1] = __builtin_amdgcn_mfma_f32_16x16x32_bf16(af0.s, b1, acc[1], 0, 0, 0);
    acc[2] = __builtin_amdgcn_mfma_f32_16x16x32_bf16(af0.s, b2, acc[2], 0, 0, 0);
    acc[3] = __builtin_amdgcn_mfma_f32_16x16x32_bf16(af0.s, b3, acc[3], 0, 0, 0);
    acc[0] = __builtin_amdgcn_mfma_f32_16x16x32_bf16(af1.s, b4, acc[0], 0, 0, 0);
    acc[1] = __builtin_amdgcn_mfma_f32_16x16x32_bf16(af1.s, b5, acc[1], 0, 0, 0);
    acc[2] = __builtin_amdgcn_mfma_f32_16x16x32_bf16(af1.s, b6, acc[2], 0, 0, 0);
    acc[3] = __builtin_amdgcn_mfma_f32_16x16x32_bf16(af1.s, b7, acc[3], 0, 0, 0);

    // write staged data to the other buffer (compiler inserts vmcnt waits)
    *(uint4*)&Bt[nxt][0][skg][scol][skw * 8] = ga;
    *(uint4*)&Bt[nxt][1][skg][scol][skw * 8] = gb;
    if (t < 64) *(float4*)&Ct[nxt][pc][kgc][jic] = gc;
    __syncthreads();
  }

  // per-kg row sums (both wn waves hold the FULL sum -> only wn==0 publishes)
  rs += __shfl_xor(rs, 16, 64);
  rs += __shfl_xor(rs, 32, 64);
  if (wn == 0 && lane < 16) rs2[kg][wm * 16 + lane] = rs;

  // kg=1 publishes its partial acc
  if (kg == 1) {
    int mre = wm * 16 + (lane >> 4) * 4;
    #pragma unroll
    for (int r = 0; r < 4; ++r) {
      comb[mre + r][n0]      = acc[0][r];
      comb[mre + r][n0 + 16] = acc[1][r];
      comb[mre + r][n0 + 32] = acc[2][r];
      comb[mre + r][n0 + 48] = acc[3][r];
    }
  }
  __syncthreads();
  if (t < 64) {
    float r = rs2[0][t] + rs2[1][t];
    float v = validf[i0 + t];
    scale_s[t] = (v > 0.f) ? 1.0f / fmaxf(r, 1e-30f) : 0.f;
  }
  __syncthreads();
  if (kg == 0) {
    int mre = wm * 16 + (lane >> 4) * 4;
    #pragma unroll
    for (int r = 0; r < 4; ++r) {
      float s = scale_s[mre + r];
      size_t base = (size_t)(i0 + mre + r) * A + colhalf * 128;
      out[base + n0]      = (acc[0][r] + comb[mre + r][n0]) * s;
      out[base + n0 + 16] = (acc[1][r] + comb[mre + r][n0 + 16]) * s;
      out[base + n0 + 32] = (acc[2][r] + comb[mre + r][n0 + 32]) * s;
      out[base + n0 + 48] = (acc[3][r] + comb[mre + r][n0 + 48]) * s;
    }
  }
}

extern "C" void kernel_launch(void* const* d_in, const int* in_sizes, int n_in,
                              void* d_out, int out_size, void* d_ws, size_t ws_size,
                              hipStream_t stream) {
  // inputs: 0 batch[S,F] 1 xywh[S,4] 2 OW 3 OH 4 actor_weights[S] 5 avg_pos[S,2]
  //         6 W_h[F,2] 7 b_h[2] 8 W_g[F,A] 9 b_g[A] 10 num_person
  const float* batch = (const float*)d_in[0];
  const float* xywh  = (const float*)d_in[1];
  const float* W_h   = (const float*)d_in[6];
  const float* b_h   = (const float*)d_in[7];
  const float* W_g   = (const float*)d_in[8];
  const float* b_g   = (const float*)d_in[9];
  int S = in_sizes[4];
  int F = in_sizes[0] / S;
  int A = in_sizes[9];

  float* out    = (float*)d_out;
  float* out_tw = out;                        // [S,A]
  float* out_hp = out + (size_t)S * A;        // [S,2]

  // workspace: tgt2 bf16 [S/32][A][32], WgT bf16 [A][F], hx/hy/validf, cxy
  uint16_t* tgt2 = (uint16_t*)d_ws;
  uint16_t* WgT  = tgt2 + (size_t)A * S;
  float* hxv = (float*)(WgT + (size_t)A * F);
  float* hyv = hxv + S;
  float* vfv = hyv + S;
  float2* cxyv = (float2*)(vfv + S);

  k_head<<<dim3((S + 3) / 4), 256, 0, stream>>>(batch, xywh, W_h, b_h,
                                                out_hp, hxv, hyv, vfv, cxyv, S, F);
  k_prep_w<<<dim3((A * F / 8 + 255) / 256), 256, 0, stream>>>(W_g, WgT, F, A);
  k_targets_mfma<<<dim3(S / 32), 256, 0, stream>>>(batch, WgT, b_g, tgt2, S, F, A);
  k_gather_v14<<<dim3(2, S / 64), 1024, 0, stream>>>(tgt2, cxyv, hxv, hyv, vfv,
                                                     out_tw, S, A);
}

// Round 15
// 148.887 us; speedup vs baseline: 2.1406x; 2.1406x over previous
//
#include <hip/hip_runtime.h>
#include <math.h>
#include <stdint.h>

typedef __attribute__((ext_vector_type(8))) short short8;
typedef __attribute__((ext_vector_type(4))) float f32x4;

__device__ __forceinline__ uint32_t cvt_pk_bf16(float lo, float hi) {
  uint32_t r;
  asm("v_cvt_pk_bf16_f32 %0, %1, %2" : "=v"(r) : "v"(lo), "v"(hi));
  return r;
}

// inverse-distance weight; invalid j has cx=cy=1e30 -> d2 overflows to inf
// -> rcp(inf)=0, so invalid columns contribute exactly 0.
__device__ __forceinline__ float wfun(float hx, float hy, float cx, float cy) {
  float dx = hx - cx, dy = hy - cy;
  float d = __builtin_amdgcn_sqrtf(fmaf(dx, dx, dy * dy));
  return __builtin_amdgcn_rcpf(d + 1e-4f);
}

// ---------------------------------------------------------------------------
// Kernel 1: hp = tanh(batch@W_h + b_h); hx,hy,validf,cxy per row. (verified)
__global__ __launch_bounds__(256) void k_head(
    const float* __restrict__ batch, const float* __restrict__ xywh,
    const float* __restrict__ W_h, const float* __restrict__ b_h,
    float* __restrict__ hp_out, float* __restrict__ hx, float* __restrict__ hy,
    float* __restrict__ validf, float2* __restrict__ cxy, int S, int F) {
  int wid = threadIdx.x >> 6;
  int lane = threadIdx.x & 63;
  int row = blockIdx.x * 4 + wid;
  if (row >= S) return;
  const float4* brow = (const float4*)(batch + (size_t)row * F);
  const float4* wh4 = (const float4*)W_h;  // W_h is [F,2] row-major
  int nf4 = F >> 2;
  float acc0 = 0.f, acc1 = 0.f;
  for (int k4 = lane; k4 < nf4; k4 += 64) {
    float4 b = brow[k4];
    float4 wa = wh4[2 * k4];
    float4 wb = wh4[2 * k4 + 1];
    acc0 += b.x * wa.x + b.y * wa.z + b.z * wb.x + b.w * wb.z;
    acc1 += b.x * wa.y + b.y * wa.w + b.z * wb.y + b.w * wb.w;
  }
  #pragma unroll
  for (int off = 32; off; off >>= 1) {
    acc0 += __shfl_xor(acc0, off, 64);
    acc1 += __shfl_xor(acc1, off, 64);
  }
  if (lane == 0) {
    float hp0 = tanhf(acc0 + b_h[0]);
    float hp1 = tanhf(acc1 + b_h[1]);
    float4 xy = ((const float4*)xywh)[row];
    hp_out[2 * row] = hp0;
    hp_out[2 * row + 1] = hp1;
    hx[row] = hp0 * xy.z * 4.0f + xy.x;  // SIGMA_X = 4
    hy[row] = hp1 * xy.w * 1.0f + xy.y;  // SIGMA_Y = 1
    bool v = (xy.x + xy.y + xy.z + xy.w >= 1e-8f);
    validf[row] = v ? 1.0f : 0.0f;
    cxy[row] = v ? make_float2(xy.x, xy.y) : make_float2(1e30f, 1e30f);
  }
}

// ---------------------------------------------------------------------------
// Kernel 1b: WgT[a][k] = bf16(Wg[k][a])  (verified)
__global__ __launch_bounds__(256) void k_prep_w(
    const float* __restrict__ Wg, uint16_t* __restrict__ WgT, int F, int A) {
  int idx = blockIdx.x * 256 + threadIdx.x;
  int a = idx % A;
  int k0 = (idx / A) * 8;
  if (k0 >= F) return;
  float f[8];
  #pragma unroll
  for (int e = 0; e < 8; ++e) f[e] = Wg[(size_t)(k0 + e) * A + a];
  uint4 v;
  v.x = cvt_pk_bf16(f[0], f[1]);
  v.y = cvt_pk_bf16(f[2], f[3]);
  v.z = cvt_pk_bf16(f[4], f[5]);
  v.w = cvt_pk_bf16(f[6], f[7]);
  *(uint4*)(WgT + (size_t)a * F + k0) = v;
}

// ---------------------------------------------------------------------------
// Kernel 2: targets via bf16 MFMA; tiled output tgt2[jb][a][jj]. (verified)
__global__ __launch_bounds__(256) void k_targets_mfma(
    const float* __restrict__ batch, const uint16_t* __restrict__ WgT,
    const float* __restrict__ bg, uint16_t* __restrict__ tgt2,
    int S, int F, int A) {
  int t = threadIdx.x;
  int lane = t & 63, wid = t >> 6;
  int wm = wid >> 1, wn = wid & 1;
  int i0 = blockIdx.x * 32;
  int row = i0 + wm * 16 + (lane & 15);
  int kch = lane >> 4;
  const float* ab = batch + (size_t)row * F + kch * 8;
  int ncol0 = wn * 128 + (lane & 15);
  const uint16_t* bb = WgT + (size_t)ncol0 * F + kch * 8;

  f32x4 acc[8] = {};
  float4 a0 = *(const float4*)(ab);
  float4 a1 = *(const float4*)(ab + 4);
  short8 bf[8];
  #pragma unroll
  for (int nf = 0; nf < 8; ++nf)
    bf[nf] = *(const short8*)(bb + (size_t)nf * 16 * F);

  for (int k0 = 0; k0 < F; k0 += 32) {
    int kn = (k0 + 32 < F) ? k0 + 32 : 0;  // wrap prefetch (harmless)
    float4 na0 = *(const float4*)(ab + kn);
    float4 na1 = *(const float4*)(ab + kn + 4);
    short8 nbf[8];
    #pragma unroll
    for (int nf = 0; nf < 8; ++nf)
      nbf[nf] = *(const short8*)(bb + kn + (size_t)nf * 16 * F);
    union { short8 s; uint32_t u[4]; } af;
    af.u[0] = cvt_pk_bf16(a0.x, a0.y);
    af.u[1] = cvt_pk_bf16(a0.z, a0.w);
    af.u[2] = cvt_pk_bf16(a1.x, a1.y);
    af.u[3] = cvt_pk_bf16(a1.z, a1.w);
    #pragma unroll
    for (int nf = 0; nf < 8; ++nf)
      acc[nf] = __builtin_amdgcn_mfma_f32_16x16x32_bf16(af.s, bf[nf], acc[nf], 0, 0, 0);
    a0 = na0; a1 = na1;
    #pragma unroll
    for (int nf = 0; nf < 8; ++nf) bf[nf] = nbf[nf];
  }

  int jb = blockIdx.x;
  int rloc = wm * 16 + (lane >> 4) * 4;   // row within tile, mult of 4
  #pragma unroll
  for (int nf = 0; nf < 8; ++nf) {
    int col = ncol0 + nf * 16;
    float b = bg[col];
    float o0 = fmaxf(acc[nf][0] + b, 0.f);
    float o1 = fmaxf(acc[nf][1] + b, 0.f);
    float o2 = fmaxf(acc[nf][2] + b, 0.f);
    float o3 = fmaxf(acc[nf][3] + b, 0.f);
    uint2 pk;
    pk.x = cvt_pk_bf16(o0, o1);
    pk.y = cvt_pk_bf16(o2, o3);
    *(uint2*)(tgt2 + ((size_t)jb * A + col) * 32 + rloc) = pk;
  }
}

// ---------------------------------------------------------------------------
// Kernel 3: out = rownorm(W) @ targets. Round-13 pipeline (113 us verified,
// stride 40 = 16B-aligned b128 reads — stride 36 was the v9/v11/v12/v14
// killer: 72 B cols put odd-n0 lanes at 8-mod-16 addrs -> misaligned b128).
// ONE delta vs v13: geometry BM=128 x BN=64 (grid (A/64, S/128)=256).
//  - per-CU B-staging instrs halve: per double-step each thread stages
//    exactly ONE uint4 (parity=t>>9, kg=(t>>8)&1) -> 512 instr/j-tile.
//  - zero within-block w-gen duplication (8 wm-waves cover distinct rows).
__global__ __launch_bounds__(1024, 4) void k_gather_v15(
    const uint16_t* __restrict__ tgt2, const float2* __restrict__ cxy,
    const float* __restrict__ hx, const float* __restrict__ hy,
    const float* __restrict__ validf, float* __restrict__ out, int S, int A) {
  __shared__ uint16_t Bt[2][2][2][64][40]; // [dbuf][parity][kg][col][40hw] 40KB
  __shared__ float2  Ct[2][2][2][32];      // [dbuf][parity][kg][jj]        2KB
  __shared__ float comb[128][68];          // kg=1 partial acc              34KB
  __shared__ float rs2[2][128];
  __shared__ float scale_s[128];

  int t = threadIdx.x;
  int lane = t & 63, wid = t >> 6;
  int kg = wid >> 3;                // 0..1
  int wm = wid & 7;                 // 0..7 (8 M-slices of 16 rows)
  int colgroup = blockIdx.x;        // 0..3
  int i0 = blockIdx.y * 128;
  int mrow = i0 + wm * 16 + (lane & 15);
  int kch = lane >> 4;
  float hx_i = hx[mrow], hy_i = hy[mrow];
  int n0 = lane & 15;                          // col within 64-group
  int NT = (S >> 1) / 32;                      // 128 tiles per K-group
  int nsteps = NT >> 1;                        // 64 double-steps
  const size_t TSTRIDE = (size_t)A * 32;       // elements per j-tile
  const int COLS = 40;                         // Bt col stride in halfwords

  // staging: each thread stages ONE uint4 per double-step.
  int sp  = t >> 9;                 // parity 0..1
  int skg = (t >> 8) & 1;           // kg 0..1
  int su  = t & 255;
  int scol = su >> 2;               // 0..63
  int skw  = su & 3;                // 16-B quarter of the 64-B column
  const uint16_t* gB0 = tgt2 + (size_t)(skg * NT + sp) * TSTRIDE
                        + (size_t)(colgroup * 64 + scol) * 32 + skw * 8;
  int kgc = (t >> 4) & 1;           // c-staging: kg of this c-thread
  int pc  = t >> 5;                 // c-staging: parity (t<64 only)
  int jic = (t & 15) * 2;
  const float2* gC0 = cxy + (size_t)kgc * (S >> 1) + pc * 32 + jic;

  f32x4 acc[4] = {};
  float rs = 0.f;

  // prologue: stage double-step 0
  {
    uint4 ga = *(const uint4*)(gB0);
    *(uint4*)&Bt[0][sp][skg][scol][skw * 8] = ga;
    if (t < 64) {
      float4 gc = *(const float4*)(gC0);
      *(float4*)&Ct[0][pc][kgc][jic] = gc;
    }
  }
  __syncthreads();

  for (int ts = 0; ts < nsteps; ++ts) {
    int cur = ts & 1, nxt = cur ^ 1;
    int tn = (ts + 1 < nsteps) ? ts + 1 : 0;   // wrap stage (harmless)

    // issue next-double-step global loads (latency hidden by compute)
    uint4 ga = *(const uint4*)(gB0 + (size_t)(2 * tn) * TSTRIDE);
    float4 gc;
    if (t < 64) gc = *(const float4*)(gC0 + tn * 64);

    // c from LDS (broadcast within 16-lane groups), both parities
    const float2* cp0 = &Ct[cur][0][kg][kch * 8];
    const float2* cp1 = &Ct[cur][1][kg][kch * 8];
    float4 c0 = *(const float4*)(cp0);
    float4 c1 = *(const float4*)(cp0 + 2);
    float4 c2 = *(const float4*)(cp0 + 4);
    float4 c3 = *(const float4*)(cp0 + 6);
    float4 c4 = *(const float4*)(cp1);
    float4 c5 = *(const float4*)(cp1 + 2);
    float4 c6 = *(const float4*)(cp1 + 4);
    float4 c7 = *(const float4*)(cp1 + 6);

    // B frags from LDS, both parities (stride-40 aligned pattern)
    const uint16_t* br0 = &Bt[cur][0][kg][n0][kch * 8];
    const uint16_t* br1 = &Bt[cur][1][kg][n0][kch * 8];
    short8 b0 = *(const short8*)(br0);
    short8 b1 = *(const short8*)(br0 + 16 * COLS);
    short8 b2 = *(const short8*)(br0 + 32 * COLS);
    short8 b3 = *(const short8*)(br0 + 48 * COLS);
    short8 b4 = *(const short8*)(br1);
    short8 b5 = *(const short8*)(br1 + 16 * COLS);
    short8 b6 = *(const short8*)(br1 + 32 * COLS);
    short8 b7 = *(const short8*)(br1 + 48 * COLS);

    // 16 w's: 8 per parity tile (A layout row=lane&15, k=(lane>>4)*8+e)
    float w0 = wfun(hx_i, hy_i, c0.x, c0.y);
    float w1 = wfun(hx_i, hy_i, c0.z, c0.w);
    float w2 = wfun(hx_i, hy_i, c1.x, c1.y);
    float w3 = wfun(hx_i, hy_i, c1.z, c1.w);
    float w4 = wfun(hx_i, hy_i, c2.x, c2.y);
    float w5 = wfun(hx_i, hy_i, c2.z, c2.w);
    float w6 = wfun(hx_i, hy_i, c3.x, c3.y);
    float w7 = wfun(hx_i, hy_i, c3.z, c3.w);
    float w8 = wfun(hx_i, hy_i, c4.x, c4.y);
    float w9 = wfun(hx_i, hy_i, c4.z, c4.w);
    float wa = wfun(hx_i, hy_i, c5.x, c5.y);
    float wb = wfun(hx_i, hy_i, c5.z, c5.w);
    float wc = wfun(hx_i, hy_i, c6.x, c6.y);
    float wd = wfun(hx_i, hy_i, c6.z, c6.w);
    float we = wfun(hx_i, hy_i, c7.x, c7.y);
    float wf = wfun(hx_i, hy_i, c7.z, c7.w);
    rs += (((w0 + w1) + (w2 + w3)) + ((w4 + w5) + (w6 + w7)))
        + (((w8 + w9) + (wa + wb)) + ((wc + wd) + (we + wf)));
    union { short8 s; uint32_t u[4]; } af0, af1;
    af0.u[0] = cvt_pk_bf16(w0, w1);
    af0.u[1] = cvt_pk_bf16(w2, w3);
    af0.u[2] = cvt_pk_bf16(w4, w5);
    af0.u[3] = cvt_pk_bf16(w6, w7);
    af1.u[0] = cvt_pk_bf16(w8, w9);
    af1.u[1] = cvt_pk_bf16(wa, wb);
    af1.u[2] = cvt_pk_bf16(wc, wd);
    af1.u[3] = cvt_pk_bf16(we, wf);

    acc[0] = __builtin_amdgcn_mfma_f32_16x16x32_bf16(af0.s, b0, acc[0], 0, 0, 0);
    acc[1] = __builtin_amdgcn_mfma_f32_16x16x32_bf16(af0.s, b1, acc[1], 0, 0, 0);
    acc[2] = __builtin_amdgcn_mfma_f32_16x16x32_bf16(af0.s, b2, acc[2], 0, 0, 0);
    acc[3] = __builtin_amdgcn_mfma_f32_16x16x32_bf16(af0.s, b3, acc[3], 0, 0, 0);
    acc[0] = __builtin_amdgcn_mfma_f32_16x16x32_bf16(af1.s, b4, acc[0], 0, 0, 0);
    acc[1] = __builtin_amdgcn_mfma_f32_16x16x32_bf16(af1.s, b5, acc[1], 0, 0, 0);
    acc[2] = __builtin_amdgcn_mfma_f32_16x16x32_bf16(af1.s, b6, acc[2], 0, 0, 0);
    acc[3] = __builtin_amdgcn_mfma_f32_16x16x32_bf16(af1.s, b7, acc[3], 0, 0, 0);

    // write staged data to the other buffer (compiler inserts vmcnt waits)
    *(uint4*)&Bt[nxt][sp][skg][scol][skw * 8] = ga;
    if (t < 64) *(float4*)&Ct[nxt][pc][kgc][jic] = gc;
    __syncthreads();
  }

  // per-kg row sums: each (kg, wm) owns distinct rows — no duplication
  rs += __shfl_xor(rs, 16, 64);
  rs += __shfl_xor(rs, 32, 64);
  if (lane < 16) rs2[kg][wm * 16 + lane] = rs;

  // kg=1 publishes its partial acc
  if (kg == 1) {
    int mre = wm * 16 + (lane >> 4) * 4;
    #pragma unroll
    for (int r = 0; r < 4; ++r) {
      comb[mre + r][n0]      = acc[0][r];
      comb[mre + r][n0 + 16] = acc[1][r];
      comb[mre + r][n0 + 32] = acc[2][r];
      comb[mre + r][n0 + 48] = acc[3][r];
    }
  }
  __syncthreads();
  if (t < 128) {
    float r = rs2[0][t] + rs2[1][t];
    float v = validf[i0 + t];
    scale_s[t] = (v > 0.f) ? 1.0f / fmaxf(r, 1e-30f) : 0.f;
  }
  __syncthreads();
  if (kg == 0) {
    int mre = wm * 16 + (lane >> 4) * 4;
    #pragma unroll
    for (int r = 0; r < 4; ++r) {
      float s = scale_s[mre + r];
      size_t base = (size_t)(i0 + mre + r) * A + colgroup * 64;
      out[base + n0]      = (acc[0][r] + comb[mre + r][n0]) * s;
      out[base + n0 + 16] = (acc[1][r] + comb[mre + r][n0 + 16]) * s;
      out[base + n0 + 32] = (acc[2][r] + comb[mre + r][n0 + 32]) * s;
      out[base + n0 + 48] = (acc[3][r] + comb[mre + r][n0 + 48]) * s;
    }
  }
}

extern "C" void kernel_launch(void* const* d_in, const int* in_sizes, int n_in,
                              void* d_out, int out_size, void* d_ws, size_t ws_size,
                              hipStream_t stream) {
  // inputs: 0 batch[S,F] 1 xywh[S,4] 2 OW 3 OH 4 actor_weights[S] 5 avg_pos[S,2]
  //         6 W_h[F,2] 7 b_h[2] 8 W_g[F,A] 9 b_g[A] 10 num_person
  const float* batch = (const float*)d_in[0];
  const float* xywh  = (const float*)d_in[1];
  const float* W_h   = (const float*)d_in[6];
  const float* b_h   = (const float*)d_in[7];
  const float* W_g   = (const float*)d_in[8];
  const float* b_g   = (const float*)d_in[9];
  int S = in_sizes[4];
  int F = in_sizes[0] / S;
  int A = in_sizes[9];

  float* out    = (float*)d_out;
  float* out_tw = out;                        // [S,A]
  float* out_hp = out + (size_t)S * A;        // [S,2]

  // workspace: tgt2 bf16 [S/32][A][32], WgT bf16 [A][F], hx/hy/validf, cxy
  uint16_t* tgt2 = (uint16_t*)d_ws;
  uint16_t* WgT  = tgt2 + (size_t)A * S;
  float* hxv = (float*)(WgT + (size_t)A * F);
  float* hyv = hxv + S;
  float* vfv = hyv + S;
  float2* cxyv = (float2*)(vfv + S);

  k_head<<<dim3((S + 3) / 4), 256, 0, stream>>>(batch, xywh, W_h, b_h,
                                                out_hp, hxv, hyv, vfv, cxyv, S, F);
  k_prep_w<<<dim3((A * F / 8 + 255) / 256), 256, 0, stream>>>(W_g, WgT, F, A);
  k_targets_mfma<<<dim3(S / 32), 256, 0, stream>>>(batch, WgT, b_g, tgt2, S, F, A);
  k_gather_v15<<<dim3(A / 64, S / 128), 1024, 0, stream>>>(tgt2, cxyv, hxv, hyv,
                                                           vfv, out_tw, S, A);
}

// Round 16
// 145.647 us; speedup vs baseline: 2.1882x; 1.0222x over previous
//
#include <hip/hip_runtime.h>
#include <math.h>
#include <stdint.h>

typedef __attribute__((ext_vector_type(8))) short short8;
typedef __attribute__((ext_vector_type(4))) float f32x4;

__device__ __forceinline__ uint32_t cvt_pk_bf16(float lo, float hi) {
  uint32_t r;
  asm("v_cvt_pk_bf16_f32 %0, %1, %2" : "=v"(r) : "v"(lo), "v"(hi));
  return r;
}

// inverse-distance weight; invalid j has cx=cy=1e30 -> d2 overflows to inf
// -> rcp(inf)=0, so invalid columns contribute exactly 0.
__device__ __forceinline__ float wfun(float hx, float hy, float cx, float cy) {
  float dx = hx - cx, dy = hy - cy;
  float d = __builtin_amdgcn_sqrtf(fmaf(dx, dx, dy * dy));
  return __builtin_amdgcn_rcpf(d + 1e-4f);
}

// ---------------------------------------------------------------------------
// Kernel 1: hp = tanh(batch@W_h + b_h); hx,hy,validf,cxy per row. (verified)
__global__ __launch_bounds__(256) void k_head(
    const float* __restrict__ batch, const float* __restrict__ xywh,
    const float* __restrict__ W_h, const float* __restrict__ b_h,
    float* __restrict__ hp_out, float* __restrict__ hx, float* __restrict__ hy,
    float* __restrict__ validf, float2* __restrict__ cxy, int S, int F) {
  int wid = threadIdx.x >> 6;
  int lane = threadIdx.x & 63;
  int row = blockIdx.x * 4 + wid;
  if (row >= S) return;
  const float4* brow = (const float4*)(batch + (size_t)row * F);
  const float4* wh4 = (const float4*)W_h;  // W_h is [F,2] row-major
  int nf4 = F >> 2;
  float acc0 = 0.f, acc1 = 0.f;
  for (int k4 = lane; k4 < nf4; k4 += 64) {
    float4 b = brow[k4];
    float4 wa = wh4[2 * k4];
    float4 wb = wh4[2 * k4 + 1];
    acc0 += b.x * wa.x + b.y * wa.z + b.z * wb.x + b.w * wb.z;
    acc1 += b.x * wa.y + b.y * wa.w + b.z * wb.y + b.w * wb.w;
  }
  #pragma unroll
  for (int off = 32; off; off >>= 1) {
    acc0 += __shfl_xor(acc0, off, 64);
    acc1 += __shfl_xor(acc1, off, 64);
  }
  if (lane == 0) {
    float hp0 = tanhf(acc0 + b_h[0]);
    float hp1 = tanhf(acc1 + b_h[1]);
    float4 xy = ((const float4*)xywh)[row];
    hp_out[2 * row] = hp0;
    hp_out[2 * row + 1] = hp1;
    hx[row] = hp0 * xy.z * 4.0f + xy.x;  // SIGMA_X = 4
    hy[row] = hp1 * xy.w * 1.0f + xy.y;  // SIGMA_Y = 1
    bool v = (xy.x + xy.y + xy.z + xy.w >= 1e-8f);
    validf[row] = v ? 1.0f : 0.0f;
    cxy[row] = v ? make_float2(xy.x, xy.y) : make_float2(1e30f, 1e30f);
  }
}

// ---------------------------------------------------------------------------
// Kernel 1b: WgT[a][k] = bf16(Wg[k][a])  (verified)
__global__ __launch_bounds__(256) void k_prep_w(
    const float* __restrict__ Wg, uint16_t* __restrict__ WgT, int F, int A) {
  int idx = blockIdx.x * 256 + threadIdx.x;
  int a = idx % A;
  int k0 = (idx / A) * 8;
  if (k0 >= F) return;
  float f[8];
  #pragma unroll
  for (int e = 0; e < 8; ++e) f[e] = Wg[(size_t)(k0 + e) * A + a];
  uint4 v;
  v.x = cvt_pk_bf16(f[0], f[1]);
  v.y = cvt_pk_bf16(f[2], f[3]);
  v.z = cvt_pk_bf16(f[4], f[5]);
  v.w = cvt_pk_bf16(f[6], f[7]);
  *(uint4*)(WgT + (size_t)a * F + k0) = v;
}

// ---------------------------------------------------------------------------
// Kernel 2: targets via bf16 MFMA; tiled output tgt2[jb][a][jj]. (verified)
__global__ __launch_bounds__(256) void k_targets_mfma(
    const float* __restrict__ batch, const uint16_t* __restrict__ WgT,
    const float* __restrict__ bg, uint16_t* __restrict__ tgt2,
    int S, int F, int A) {
  int t = threadIdx.x;
  int lane = t & 63, wid = t >> 6;
  int wm = wid >> 1, wn = wid & 1;
  int i0 = blockIdx.x * 32;
  int row = i0 + wm * 16 + (lane & 15);
  int kch = lane >> 4;
  const float* ab = batch + (size_t)row * F + kch * 8;
  int ncol0 = wn * 128 + (lane & 15);
  const uint16_t* bb = WgT + (size_t)ncol0 * F + kch * 8;

  f32x4 acc[8] = {};
  float4 a0 = *(const float4*)(ab);
  float4 a1 = *(const float4*)(ab + 4);
  short8 bf[8];
  #pragma unroll
  for (int nf = 0; nf < 8; ++nf)
    bf[nf] = *(const short8*)(bb + (size_t)nf * 16 * F);

  for (int k0 = 0; k0 < F; k0 += 32) {
    int kn = (k0 + 32 < F) ? k0 + 32 : 0;  // wrap prefetch (harmless)
    float4 na0 = *(const float4*)(ab + kn);
    float4 na1 = *(const float4*)(ab + kn + 4);
    short8 nbf[8];
    #pragma unroll
    for (int nf = 0; nf < 8; ++nf)
      nbf[nf] = *(const short8*)(bb + kn + (size_t)nf * 16 * F);
    union { short8 s; uint32_t u[4]; } af;
    af.u[0] = cvt_pk_bf16(a0.x, a0.y);
    af.u[1] = cvt_pk_bf16(a0.z, a0.w);
    af.u[2] = cvt_pk_bf16(a1.x, a1.y);
    af.u[3] = cvt_pk_bf16(a1.z, a1.w);
    #pragma unroll
    for (int nf = 0; nf < 8; ++nf)
      acc[nf] = __builtin_amdgcn_mfma_f32_16x16x32_bf16(af.s, bf[nf], acc[nf], 0, 0, 0);
    a0 = na0; a1 = na1;
    #pragma unroll
    for (int nf = 0; nf < 8; ++nf) bf[nf] = nbf[nf];
  }

  int jb = blockIdx.x;
  int rloc = wm * 16 + (lane >> 4) * 4;   // row within tile, mult of 4
  #pragma unroll
  for (int nf = 0; nf < 8; ++nf) {
    int col = ncol0 + nf * 16;
    float b = bg[col];
    float o0 = fmaxf(acc[nf][0] + b, 0.f);
    float o1 = fmaxf(acc[nf][1] + b, 0.f);
    float o2 = fmaxf(acc[nf][2] + b, 0.f);
    float o3 = fmaxf(acc[nf][3] + b, 0.f);
    uint2 pk;
    pk.x = cvt_pk_bf16(o0, o1);
    pk.y = cvt_pk_bf16(o2, o3);
    *(uint2*)(tgt2 + ((size_t)jb * A + col) * 32 + rloc) = pk;
  }
}

// ---------------------------------------------------------------------------
// Kernel 3: out = rownorm(W) @ targets.  BM=32 x BN=256 (block owns 32 unique
// rows, ALL cols) -> w-gen duplication 1x (was 4x across colgroups).
// 16 waves = 2(kg) x 2(wm) x 4(wn). Each thread computes 2 w's/step for the
// NEXT tile (c pipelined 2 steps ahead in regs), ds_write_b32 into a
// lane-ordered Af layout; readers ds_read_b128 the exact A-fragment.
//  writer (r,jp): lane=(r&15)|((jp>>2)<<4), slot=jp&3  <=>  reader lane l,
//  slot s holds w[row=l&15][k=(l>>4)*8+2s+{0,1}]  (k=2jp checks out).
// B staging: stride-40 aligned pipeline (v13/v15-verified), 32B/thread/step.
__global__ __launch_bounds__(1024, 4) void k_gather_v16(
    const uint16_t* __restrict__ tgt2, const float2* __restrict__ cxy,
    const float* __restrict__ hx, const float* __restrict__ hy,
    const float* __restrict__ validf, float* __restrict__ out, int S, int A) {
  __shared__ uint16_t Bt[2][2][256][40];   // [dbuf][kg][col][40hw]   80 KB
  __shared__ uint32_t Af[2][2][2][64][4];  // [dbuf][kg][wm][lane][s]  8 KB
  __shared__ float comb[32][260];          // kg=1 partial acc        33.3 KB
  __shared__ float rs_l[2][32][16];        // [kg][row][jp]            4 KB
  __shared__ float scale_s[32];

  int t = threadIdx.x;
  int lane = t & 63, wid = t >> 6;
  int kg = wid >> 3;                 // 0..1 (j-half)
  int sub = wid & 7;
  int wm = sub >> 2, wn = sub & 3;   // 2M x 4N
  int i0 = blockIdx.x * 32;
  int kch = lane >> 4;
  int n0 = wn * 64 + (lane & 15);    // col 0..255
  int NT = (S >> 1) / 32;            // 128 tiles per K-group
  const size_t TSTRIDE = (size_t)A * 32;
  const int COLS = 40;

  // ---- writer role (all 1024 threads): (row wr, j-pair wjp) of kg's tile
  int u = t & 511;
  int wr = u & 31;                   // 0..31
  int wjp = u >> 5;                  // 0..15
  float hx_w = hx[i0 + wr], hy_w = hy[i0 + wr];
  uint32_t* afw0 = &Af[0][kg][wr >> 4][(wr & 15) | ((wjp >> 2) << 4)][wjp & 3];
  uint32_t* afw1 = &Af[1][kg][wr >> 4][(wr & 15) | ((wjp >> 2) << 4)][wjp & 3];
  const float2* gC = cxy + (size_t)kg * (S >> 1) + 2 * wjp;  // + tile*32

  // ---- staging role: 32 B (2 x uint4) of kg's tile per step
  int scol = u >> 1;                 // 0..255
  int skw = u & 1;                   // 0..1 (32-B half of the 64-B column)
  const uint16_t* gB0 = tgt2 + (size_t)(kg * NT) * TSTRIDE
                        + (size_t)scol * 32 + skw * 16;

  f32x4 acc[4] = {};
  float rs = 0.f;

  // ---- prologue: w(tile0) + B(tile0) into buffer 0; preload c(tile1)
  {
    float4 c0 = *(const float4*)(gC);
    float wA = wfun(hx_w, hy_w, c0.x, c0.y);
    float wB = wfun(hx_w, hy_w, c0.z, c0.w);
    rs += wA + wB;
    *afw0 = cvt_pk_bf16(wA, wB);
    uint4 ga = *(const uint4*)(gB0);
    uint4 gb = *(const uint4*)(gB0 + 8);
    *(uint4*)&Bt[0][kg][scol][skw * 16] = ga;
    *(uint4*)&Bt[0][kg][scol][skw * 16 + 8] = gb;
  }
  float4 ccur = *(const float4*)(gC + 32);   // c for tile 1
  __syncthreads();

  for (int ts = 0; ts < NT; ++ts) {
    int nxt = (ts & 1) ^ 1;
    int tn = (ts + 1 < NT) ? ts + 1 : 0;     // next tile (wrap harmless)
    int tf = (ts + 2 < NT) ? ts + 2 : 0;     // c two ahead

    // issue next-tile B loads + c(ts+2) load (latency hidden by compute)
    const uint16_t* bp = gB0 + (size_t)tn * TSTRIDE;
    uint4 ga = *(const uint4*)(bp);
    uint4 gb = *(const uint4*)(bp + 8);
    float4 cfut = *(const float4*)(gC + (size_t)tf * 32);

    // read A-frag + B-frags for current tile
    const uint32_t* afp = &Af[ts & 1][kg][wm][lane][0];
    short8 afr = *(const short8*)afp;
    const uint16_t* br = &Bt[ts & 1][kg][n0][kch * 8];
    short8 b0 = *(const short8*)(br);
    short8 b1 = *(const short8*)(br + 16 * COLS);
    short8 b2 = *(const short8*)(br + 32 * COLS);
    short8 b3 = *(const short8*)(br + 48 * COLS);

    acc[0] = __builtin_amdgcn_mfma_f32_16x16x32_bf16(afr, b0, acc[0], 0, 0, 0);
    acc[1] = __builtin_amdgcn_mfma_f32_16x16x32_bf16(afr, b1, acc[1], 0, 0, 0);
    acc[2] = __builtin_amdgcn_mfma_f32_16x16x32_bf16(afr, b2, acc[2], 0, 0, 0);
    acc[3] = __builtin_amdgcn_mfma_f32_16x16x32_bf16(afr, b3, acc[3], 0, 0, 0);

    // w-gen for tile ts+1 (skip rs on the wrapped last step)
    float wA = wfun(hx_w, hy_w, ccur.x, ccur.y);
    float wB = wfun(hx_w, hy_w, ccur.z, ccur.w);
    float g = (ts + 1 < NT) ? 1.f : 0.f;
    rs = fmaf(g, wA + wB, rs);
    uint32_t pk = cvt_pk_bf16(wA, wB);
    uint32_t* afw = nxt ? afw1 : afw0;
    *afw = pk;

    // write staged B to the other buffer
    *(uint4*)&Bt[nxt][kg][scol][skw * 16] = ga;
    *(uint4*)&Bt[nxt][kg][scol][skw * 16 + 8] = gb;
    ccur = cfut;
    __syncthreads();
  }

  // ---- rowsum: per-thread (kg,row,jp) partials -> LDS reduce
  rs_l[kg][wr][wjp] = rs;

  // kg=1 publishes its partial acc
  if (kg == 1) {
    int mre = wm * 16 + (lane >> 4) * 4;
    #pragma unroll
    for (int r = 0; r < 4; ++r) {
      comb[mre + r][n0]      = acc[0][r];
      comb[mre + r][n0 + 16] = acc[1][r];
      comb[mre + r][n0 + 32] = acc[2][r];
      comb[mre + r][n0 + 48] = acc[3][r];
    }
  }
  __syncthreads();
  if (t < 32) {
    float r = 0.f;
    #pragma unroll
    for (int jp = 0; jp < 16; ++jp) r += rs_l[0][t][jp] + rs_l[1][t][jp];
    float v = validf[i0 + t];
    scale_s[t] = (v > 0.f) ? 1.0f / fmaxf(r, 1e-30f) : 0.f;
  }
  __syncthreads();
  if (kg == 0) {
    int mre = wm * 16 + (lane >> 4) * 4;
    #pragma unroll
    for (int r = 0; r < 4; ++r) {
      float s = scale_s[mre + r];
      size_t base = (size_t)(i0 + mre + r) * A;
      out[base + n0]      = (acc[0][r] + comb[mre + r][n0]) * s;
      out[base + n0 + 16] = (acc[1][r] + comb[mre + r][n0 + 16]) * s;
      out[base + n0 + 32] = (acc[2][r] + comb[mre + r][n0 + 32]) * s;
      out[base + n0 + 48] = (acc[3][r] + comb[mre + r][n0 + 48]) * s;
    }
  }
}

extern "C" void kernel_launch(void* const* d_in, const int* in_sizes, int n_in,
                              void* d_out, int out_size, void* d_ws, size_t ws_size,
                              hipStream_t stream) {
  // inputs: 0 batch[S,F] 1 xywh[S,4] 2 OW 3 OH 4 actor_weights[S] 5 avg_pos[S,2]
  //         6 W_h[F,2] 7 b_h[2] 8 W_g[F,A] 9 b_g[A] 10 num_person
  const float* batch = (const float*)d_in[0];
  const float* xywh  = (const float*)d_in[1];
  const float* W_h   = (const float*)d_in[6];
  const float* b_h   = (const float*)d_in[7];
  const float* W_g   = (const float*)d_in[8];
  const float* b_g   = (const float*)d_in[9];
  int S = in_sizes[4];
  int F = in_sizes[0] / S;
  int A = in_sizes[9];

  float* out    = (float*)d_out;
  float* out_tw = out;                        // [S,A]
  float* out_hp = out + (size_t)S * A;        // [S,2]

  // workspace: tgt2 bf16 [S/32][A][32], WgT bf16 [A][F], hx/hy/validf, cxy
  uint16_t* tgt2 = (uint16_t*)d_ws;
  uint16_t* WgT  = tgt2 + (size_t)A * S;
  float* hxv = (float*)(WgT + (size_t)A * F);
  float* hyv = hxv + S;
  float* vfv = hyv + S;
  float2* cxyv = (float2*)(vfv + S);

  k_head<<<dim3((S + 3) / 4), 256, 0, stream>>>(batch, xywh, W_h, b_h,
                                                out_hp, hxv, hyv, vfv, cxyv, S, F);
  k_prep_w<<<dim3((A * F / 8 + 255) / 256), 256, 0, stream>>>(W_g, WgT, F, A);
  k_targets_mfma<<<dim3(S / 32), 256, 0, stream>>>(batch, WgT, b_g, tgt2, S, F, A);
  k_gather_v16<<<dim3(S / 32), 1024, 0, stream>>>(tgt2, cxyv, hxv, hyv, vfv,
                                                  out_tw, S, A);
}